// Round 6
// baseline (413.862 us; speedup 1.0000x reference)
//
#include <hip/hip_runtime.h>
#include <hip/hip_bf16.h>

#define E 128
#define F 128
#define O 64
#define K 8
#define BATCH 2048
#define NEWTON_IT 7

typedef __attribute__((ext_vector_type(8))) short bf8;     // 8 bf16 (4 VGPR)
typedef __attribute__((ext_vector_type(16))) float f16x;   // MFMA 32x32 accumulator

// ---------------------------------------------------------------------------
// Kernel A: M[k,o,x] = 0.5 * sum_y bil[k,x,y] * Q[k,o,y], stored as truncated
// bf16 hi/lo planes in FRAGMENT-MAJOR layout: [k][(s*2+h)][o][8] where
// x = s*16 + h*8 + e.  Kernel B's A-loads are then lane-coalesced.
// ---------------------------------------------------------------------------
__global__ __launch_bounds__(256) void precompute_M(const float* __restrict__ Q,
                                                    const float* __restrict__ bil,
                                                    unsigned short* __restrict__ Mhi,
                                                    unsigned short* __restrict__ Mlo) {
    int idx = blockIdx.x * 256 + threadIdx.x;   // ((kk*O + o)*E + x)
    int x  = idx & 127;
    int o  = (idx >> 7) & 63;
    int kk = idx >> 13;
    const float4* br = (const float4*)(bil + (size_t)(kk * E + x) * E);
    const float4* qr = (const float4*)(Q + (size_t)(kk * O + o) * E);
    float acc = 0.f;
#pragma unroll 8
    for (int y = 0; y < E / 4; ++y) {
        float4 bv = br[y], qv = qr[y];
        acc = fmaf(bv.x, qv.x, acc);
        acc = fmaf(bv.y, qv.y, acc);
        acc = fmaf(bv.z, qv.z, acc);
        acc = fmaf(bv.w, qv.w, acc);
    }
    float m = 0.5f * acc;
    unsigned um = __float_as_uint(m);
    float hi = __uint_as_float(um & 0xFFFF0000u);
    float lo = m - hi;
    int s = x >> 4, h = (x >> 3) & 1, e = x & 7;
    int nidx = kk * (O * E) + (((s * 2 + h) * 64 + o) << 3) + e;
    Mhi[nidx] = (unsigned short)(um >> 16);
    Mlo[nidx] = (unsigned short)(__float_as_uint(lo) >> 16);
}

// split a,b into truncated-bf16 hi words + lo words, packed pairwise
#define SPLIT_PK(a, b, hw, lw)                                              \
    {                                                                       \
        unsigned ua = __float_as_uint(a), ub = __float_as_uint(b);          \
        float la = (a) - __uint_as_float(ua & 0xFFFF0000u);                 \
        float lb = (b) - __uint_as_float(ub & 0xFFFF0000u);                 \
        hw = (ua >> 16) | (ub & 0xFFFF0000u);                               \
        lw = (__float_as_uint(la) >> 16) | (__float_as_uint(lb) & 0xFFFF0000u); \
    }

__device__ __forceinline__ float fastrcp(float x) {
    float r = __builtin_amdgcn_rcpf(x);
    return r * __builtin_fmaf(-x, r, 2.0f);   // 1 NR step -> ~f32-exact
}

// ---------------------------------------------------------------------------
// Kernel B: one block per b; x loaded+split ONCE, then 8 heads, software-
// pipelined: MFMA(head k) issues before Newton(head k-1) so the matrix pipe
// and L2 A-loads hide under the VALU entmax solve of the previous head.
// ---------------------------------------------------------------------------
__global__ __launch_bounds__(256, 3) void fused_entmax(
        const float* __restrict__ xg,
        const unsigned short* __restrict__ Mhi,
        const unsigned short* __restrict__ Mlo,
        const float* __restrict__ values,
        float* __restrict__ out) {
    __shared__ float lds[O * 132];           // 33792 B

    int b = blockIdx.x;
    const float* xb = xg + (size_t)b * (F * E);

    int tid  = threadIdx.x;
    int w    = tid >> 6, l = tid & 63;
    int lo31 = l & 31;
    int hl   = l >> 5;                       // K-half: x-chunk 0 or 8
    int fcol = w * 32 + lo31;

    // ---- B operand once per block: x[fcol][s*16+hl*8 .. +8), split hi/lo ----
    bf8 Bh[8], Bl[8];
#pragma unroll
    for (int s = 0; s < 8; ++s) {
        const float* p = xb + (size_t)fcol * E + s * 16 + hl * 8;
        float4 v0 = *(const float4*)p;
        float4 v1 = *(const float4*)(p + 4);
        union { bf8 v; unsigned u[4]; } H, L;
        SPLIT_PK(v0.x, v0.y, H.u[0], L.u[0]);
        SPLIT_PK(v0.z, v0.w, H.u[1], L.u[1]);
        SPLIT_PK(v1.x, v1.y, H.u[2], L.u[2]);
        SPLIT_PK(v1.z, v1.w, H.u[3], L.u[3]);
        Bh[s] = H.v;
        Bl[s] = L.v;
    }

    int orow = tid >> 2;
    int q    = tid & 3;

#define MFMA_HEAD(kh, A0, A1)                                                   \
    {                                                                           \
        const unsigned short* mh = Mhi + (size_t)(kh) * (O * E);                \
        const unsigned short* ml = Mlo + (size_t)(kh) * (O * E);                \
        _Pragma("unroll")                                                       \
        for (int st = 0; st < 8; ++st) {                                        \
            int base = ((st * 2 + hl) * 64) << 3;                               \
            bf8 a0h = *(const bf8*)(mh + base + (lo31 << 3));                   \
            bf8 a0l = *(const bf8*)(ml + base + (lo31 << 3));                   \
            bf8 a1h = *(const bf8*)(mh + base + ((lo31 + 32) << 3));            \
            bf8 a1l = *(const bf8*)(ml + base + ((lo31 + 32) << 3));            \
            A0 = __builtin_amdgcn_mfma_f32_32x32x16_bf16(a0l, Bh[st], A0, 0, 0, 0); \
            A0 = __builtin_amdgcn_mfma_f32_32x32x16_bf16(a0h, Bl[st], A0, 0, 0, 0); \
            A0 = __builtin_amdgcn_mfma_f32_32x32x16_bf16(a0h, Bh[st], A0, 0, 0, 0); \
            A1 = __builtin_amdgcn_mfma_f32_32x32x16_bf16(a1l, Bh[st], A1, 0, 0, 0); \
            A1 = __builtin_amdgcn_mfma_f32_32x32x16_bf16(a1h, Bl[st], A1, 0, 0, 0); \
            A1 = __builtin_amdgcn_mfma_f32_32x32x16_bf16(a1h, Bh[st], A1, 0, 0, 0); \
        }                                                                       \
    }

#define TRANSPOSE(A0, A1)                                                       \
    _Pragma("unroll")                                                           \
    for (int r = 0; r < 16; ++r) {                                              \
        int ol = (r & 3) + ((r >> 2) << 3) + (hl << 2);                         \
        lds[ol * 132 + fcol]        = A0[r];                                    \
        lds[(ol + 32) * 132 + fcol] = A1[r];                                    \
    }

#define ZLOAD(zz)                                                               \
    _Pragma("unroll")                                                           \
    for (int j = 0; j < 8; ++j) {                                               \
        float4 v = *(const float4*)&lds[orow * 132 + q * 4 + 16 * j];           \
        zz[4 * j + 0] = v.x; zz[4 * j + 1] = v.y;                               \
        zz[4 * j + 2] = v.z; zz[4 * j + 3] = v.w;                               \
    }

#define NEWTON_EPI(kh, zz)                                                      \
    {                                                                           \
        float m0 = zz[0], m1 = zz[1], m2 = zz[2], m3 = zz[3];                   \
        _Pragma("unroll")                                                       \
        for (int i = 4; i < 32; i += 4) {                                       \
            m0 = fmaxf(m0, zz[i]);     m1 = fmaxf(m1, zz[i + 1]);               \
            m2 = fmaxf(m2, zz[i + 2]); m3 = fmaxf(m3, zz[i + 3]);               \
        }                                                                       \
        float mx = fmaxf(fmaxf(m0, m1), fmaxf(m2, m3));                         \
        mx = fmaxf(mx, __shfl_xor(mx, 1));                                      \
        mx = fmaxf(mx, __shfl_xor(mx, 2));                                      \
        float t = mx - 1.0f;                                                    \
        _Pragma("unroll")                                                       \
        for (int it = 0; it < NEWTON_IT; ++it) {                                \
            float s0 = 0.f, s1 = 0.f, s2 = 0.f, s3 = 0.f;                       \
            float a0 = 0.f, a1 = 0.f;                                           \
            _Pragma("unroll")                                                   \
            for (int i = 0; i < 32; i += 4) {                                   \
                float d0 = fmaxf(zz[i] - t, 0.f);                               \
                float d1 = fmaxf(zz[i + 1] - t, 0.f);                           \
                float d2 = fmaxf(zz[i + 2] - t, 0.f);                           \
                float d3 = fmaxf(zz[i + 3] - t, 0.f);                           \
                s0 = __builtin_fmaf(d0, d0, s0);                                \
                s1 = __builtin_fmaf(d1, d1, s1);                                \
                s2 = __builtin_fmaf(d2, d2, s2);                                \
                s3 = __builtin_fmaf(d3, d3, s3);                                \
                a0 += d0 + d1; a1 += d2 + d3;                                   \
            }                                                                   \
            float fs = (s0 + s1) + (s2 + s3);                                   \
            float sl = a0 + a1;                                                 \
            fs += __shfl_xor(fs, 1); fs += __shfl_xor(fs, 2);                   \
            sl += __shfl_xor(sl, 1); sl += __shfl_xor(sl, 2);                   \
            t += (fs - 1.0f) * 0.5f * fastrcp(sl);                              \
        }                                                                       \
        float n0 = 0.f, n1 = 0.f, n2 = 0.f, n3 = 0.f;                           \
        _Pragma("unroll")                                                       \
        for (int i = 0; i < 32; i += 4) {                                       \
            float d0 = fmaxf(zz[i] - t, 0.f);                                   \
            float d1 = fmaxf(zz[i + 1] - t, 0.f);                               \
            float d2 = fmaxf(zz[i + 2] - t, 0.f);                               \
            float d3 = fmaxf(zz[i + 3] - t, 0.f);                               \
            d0 *= d0; d1 *= d1; d2 *= d2; d3 *= d3;                             \
            n0 += d0; n1 += d1; n2 += d2; n3 += d3;                             \
            zz[i] = d0; zz[i + 1] = d1; zz[i + 2] = d2; zz[i + 3] = d3;         \
        }                                                                       \
        float sn = (n0 + n1) + (n2 + n3);                                       \
        sn += __shfl_xor(sn, 1);                                                \
        sn += __shfl_xor(sn, 2);                                                \
        float inv = fastrcp(sn);                                                \
        const float* vr = values + (size_t)((kh) * O + orow) * F;               \
        float* op = out + (((size_t)b * K + (kh)) * O + orow) * (size_t)F;      \
        _Pragma("unroll")                                                       \
        for (int j = 0; j < 8; ++j) {                                           \
            int fb = q * 4 + 16 * j;                                            \
            float4 vv = *(const float4*)(vr + fb);                              \
            float4 ov;                                                          \
            ov.x = zz[4 * j + 0] * inv * vv.x;                                  \
            ov.y = zz[4 * j + 1] * inv * vv.y;                                  \
            ov.z = zz[4 * j + 2] * inv * vv.z;                                  \
            ov.w = zz[4 * j + 3] * inv * vv.w;                                  \
            *(float4*)(op + fb) = ov;                                           \
        }                                                                       \
    }

    // ---- head 0: fill the pipeline ----
    float z[32];
    {
        f16x acc0{}, acc1{};
        MFMA_HEAD(0, acc0, acc1);
        TRANSPOSE(acc0, acc1);
        __syncthreads();
        ZLOAD(z);
    }

    // ---- heads 1..7: MFMA(k) overlaps Newton+epilogue(k-1) ----
#pragma unroll 1
    for (int kh = 1; kh < K; ++kh) {
        f16x acc0{}, acc1{};
        MFMA_HEAD(kh, acc0, acc1);       // matrix pipe + L2 loads, independent
        NEWTON_EPI(kh - 1, z);           // VALU; scheduler interleaves the two
        __syncthreads();                 // WAR: all z-reads of head kh-1 done
        TRANSPOSE(acc0, acc1);
        __syncthreads();
        ZLOAD(z);
    }

    // ---- drain: last head's entmax ----
    NEWTON_EPI(K - 1, z);
}

extern "C" void kernel_launch(void* const* d_in, const int* in_sizes, int n_in,
                              void* d_out, int out_size, void* d_ws, size_t ws_size,
                              hipStream_t stream) {
    const float* x      = (const float*)d_in[0];   // [B, F, E]
    const float* Q      = (const float*)d_in[1];   // [K, O, E]
    const float* bil    = (const float*)d_in[2];   // [K, E, E]
    const float* values = (const float*)d_in[3];   // [K, O, F]
    float* out = (float*)d_out;                    // [B, K, O, F]

    unsigned short* Mhi = (unsigned short*)d_ws;           // [K][16][O][8] bf16 hi
    unsigned short* Mlo = Mhi + (size_t)K * O * E;         // same layout, lo

    precompute_M<<<(K * O * E) / 256, 256, 0, stream>>>(Q, bil, Mhi, Mlo);
    fused_entmax<<<BATCH, 256, 0, stream>>>(x, Mhi, Mlo, values, out);
}

// Round 7
// 349.066 us; speedup vs baseline: 1.1856x; 1.1856x over previous
//
#include <hip/hip_runtime.h>
#include <hip/hip_bf16.h>

#define E 128
#define F 128
#define O 64
#define K 8
#define BATCH 2048
#define NEWTON_IT 7

typedef __attribute__((ext_vector_type(8))) short bf8;     // 8 bf16 (4 VGPR)
typedef __attribute__((ext_vector_type(16))) float f16x;   // MFMA 32x32 accumulator

// ---------------------------------------------------------------------------
// Kernel A: M[k,o,x] = 0.5 * sum_y bil[k,x,y] * Q[k,o,y], stored as truncated
// bf16 hi/lo planes in FRAGMENT-MAJOR layout: [k][(s*2+h)][o][8] where
// x = s*16 + h*8 + e.  Kernel B's A-loads are then lane-coalesced.
// ---------------------------------------------------------------------------
__global__ __launch_bounds__(256) void precompute_M(const float* __restrict__ Q,
                                                    const float* __restrict__ bil,
                                                    unsigned short* __restrict__ Mhi,
                                                    unsigned short* __restrict__ Mlo) {
    int idx = blockIdx.x * 256 + threadIdx.x;   // ((kk*O + o)*E + x)
    int x  = idx & 127;
    int o  = (idx >> 7) & 63;
    int kk = idx >> 13;
    const float4* br = (const float4*)(bil + (size_t)(kk * E + x) * E);
    const float4* qr = (const float4*)(Q + (size_t)(kk * O + o) * E);
    float acc = 0.f;
#pragma unroll 8
    for (int y = 0; y < E / 4; ++y) {
        float4 bv = br[y], qv = qr[y];
        acc = fmaf(bv.x, qv.x, acc);
        acc = fmaf(bv.y, qv.y, acc);
        acc = fmaf(bv.z, qv.z, acc);
        acc = fmaf(bv.w, qv.w, acc);
    }
    float m = 0.5f * acc;
    unsigned um = __float_as_uint(m);
    float hi = __uint_as_float(um & 0xFFFF0000u);
    float lo = m - hi;
    int s = x >> 4, h = (x >> 3) & 1, e = x & 7;
    int nidx = kk * (O * E) + (((s * 2 + h) * 64 + o) << 3) + e;
    Mhi[nidx] = (unsigned short)(um >> 16);
    Mlo[nidx] = (unsigned short)(__float_as_uint(lo) >> 16);
}

// split a,b into truncated-bf16 hi words + lo words, packed pairwise
#define SPLIT_PK(a, b, hw, lw)                                              \
    {                                                                       \
        unsigned ua = __float_as_uint(a), ub = __float_as_uint(b);          \
        float la = (a) - __uint_as_float(ua & 0xFFFF0000u);                 \
        float lb = (b) - __uint_as_float(ub & 0xFFFF0000u);                 \
        hw = (ua >> 16) | (ub & 0xFFFF0000u);                               \
        lw = (__float_as_uint(la) >> 16) | (__float_as_uint(lb) & 0xFFFF0000u); \
    }

__device__ __forceinline__ float fastrcp(float x) {
    float r = __builtin_amdgcn_rcpf(x);
    return r * __builtin_fmaf(-x, r, 2.0f);   // 1 NR step -> ~f32-exact
}

// ---------------------------------------------------------------------------
// Kernel B: one block per b; x loaded+split ONCE into regs, then 8 heads:
// MFMA GEMM (3-product bf16 split) -> LDS transpose -> Newton entmax -> out.
// Round-5 structure (acc dead before z lives -> no spill); overlap across
// heads comes from 4 resident blocks/CU (TLP), not in-wave pipelining.
// ---------------------------------------------------------------------------
__global__ __launch_bounds__(256, 4) void fused_entmax(
        const float* __restrict__ xg,
        const unsigned short* __restrict__ Mhi,
        const unsigned short* __restrict__ Mlo,
        const float* __restrict__ values,
        float* __restrict__ out) {
    __shared__ float lds[O * 132];           // 33792 B -> 4 blocks/CU

    int b = blockIdx.x;
    const float* xb = xg + (size_t)b * (F * E);

    int tid  = threadIdx.x;
    int w    = tid >> 6, l = tid & 63;
    int lo31 = l & 31;
    int hl   = l >> 5;                       // K-half: x-chunk 0 or 8
    int fcol = w * 32 + lo31;

    // ---- B operand once per block: x[fcol][s*16+hl*8 .. +8), split hi/lo ----
    bf8 Bh[8], Bl[8];
#pragma unroll
    for (int s = 0; s < 8; ++s) {
        const float* p = xb + (size_t)fcol * E + s * 16 + hl * 8;
        float4 v0 = *(const float4*)p;
        float4 v1 = *(const float4*)(p + 4);
        union { bf8 v; unsigned u[4]; } H, L;
        SPLIT_PK(v0.x, v0.y, H.u[0], L.u[0]);
        SPLIT_PK(v0.z, v0.w, H.u[1], L.u[1]);
        SPLIT_PK(v1.x, v1.y, H.u[2], L.u[2]);
        SPLIT_PK(v1.z, v1.w, H.u[3], L.u[3]);
        Bh[s] = H.v;
        Bl[s] = L.v;
    }

    int orow = tid >> 2;
    int q    = tid & 3;

#pragma unroll 1
    for (int kh = 0; kh < K; ++kh) {
        const unsigned short* mh = Mhi + (size_t)kh * (O * E);
        const unsigned short* ml = Mlo + (size_t)kh * (O * E);

        // ---- MFMA K-loop: acc = Ah*Bh + Ah*Bl + Al*Bh (coalesced A-loads) ----
        f16x acc0{}, acc1{};
#pragma unroll
        for (int s = 0; s < 8; ++s) {
            int base = ((s * 2 + hl) * 64) << 3;
            bf8 a0h = *(const bf8*)(mh + base + (lo31 << 3));
            bf8 a0l = *(const bf8*)(ml + base + (lo31 << 3));
            bf8 a1h = *(const bf8*)(mh + base + ((lo31 + 32) << 3));
            bf8 a1l = *(const bf8*)(ml + base + ((lo31 + 32) << 3));
            acc0 = __builtin_amdgcn_mfma_f32_32x32x16_bf16(a0l, Bh[s], acc0, 0, 0, 0);
            acc0 = __builtin_amdgcn_mfma_f32_32x32x16_bf16(a0h, Bl[s], acc0, 0, 0, 0);
            acc0 = __builtin_amdgcn_mfma_f32_32x32x16_bf16(a0h, Bh[s], acc0, 0, 0, 0);
            acc1 = __builtin_amdgcn_mfma_f32_32x32x16_bf16(a1l, Bh[s], acc1, 0, 0, 0);
            acc1 = __builtin_amdgcn_mfma_f32_32x32x16_bf16(a1h, Bl[s], acc1, 0, 0, 0);
            acc1 = __builtin_amdgcn_mfma_f32_32x32x16_bf16(a1h, Bh[s], acc1, 0, 0, 0);
        }

        // ---- transpose C into lds[o][f] (stride 132) ----
        if (kh) __syncthreads();             // prev head's z-reads done
#pragma unroll
        for (int r = 0; r < 16; ++r) {
            int ol = (r & 3) + ((r >> 2) << 3) + (hl << 2);
            lds[ol * 132 + fcol]        = acc0[r];
            lds[(ol + 32) * 132 + fcol] = acc1[r];
        }
        __syncthreads();

        // ---- Newton entmax on row orow (128 elems across 4-lane quad) ----
        float z[32];
#pragma unroll
        for (int j = 0; j < 8; ++j) {
            float4 v = *(const float4*)&lds[orow * 132 + q * 4 + 16 * j];
            z[4 * j + 0] = v.x;
            z[4 * j + 1] = v.y;
            z[4 * j + 2] = v.z;
            z[4 * j + 3] = v.w;
        }

        float m0 = z[0], m1 = z[1], m2 = z[2], m3 = z[3];
#pragma unroll
        for (int i = 4; i < 32; i += 4) {
            m0 = fmaxf(m0, z[i]);
            m1 = fmaxf(m1, z[i + 1]);
            m2 = fmaxf(m2, z[i + 2]);
            m3 = fmaxf(m3, z[i + 3]);
        }
        float mx = fmaxf(fmaxf(m0, m1), fmaxf(m2, m3));
        mx = fmaxf(mx, __shfl_xor(mx, 1));
        mx = fmaxf(mx, __shfl_xor(mx, 2));

        float t = mx - 1.0f;
#pragma unroll
        for (int it = 0; it < NEWTON_IT; ++it) {
            float s0 = 0.f, s1 = 0.f, s2 = 0.f, s3 = 0.f;
            float a0 = 0.f, a1 = 0.f;
#pragma unroll
            for (int i = 0; i < 32; i += 4) {
                float d0 = fmaxf(z[i] - t, 0.f);
                float d1 = fmaxf(z[i + 1] - t, 0.f);
                float d2 = fmaxf(z[i + 2] - t, 0.f);
                float d3 = fmaxf(z[i + 3] - t, 0.f);
                s0 = __builtin_fmaf(d0, d0, s0);
                s1 = __builtin_fmaf(d1, d1, s1);
                s2 = __builtin_fmaf(d2, d2, s2);
                s3 = __builtin_fmaf(d3, d3, s3);
                a0 += d0 + d1;
                a1 += d2 + d3;
            }
            float fs = (s0 + s1) + (s2 + s3);
            float sl = a0 + a1;
            fs += __shfl_xor(fs, 1);
            fs += __shfl_xor(fs, 2);
            sl += __shfl_xor(sl, 1);
            sl += __shfl_xor(sl, 2);
            t += (fs - 1.0f) * 0.5f * fastrcp(sl);   // convex, from below
        }

        // ---- final eval: d^2 in place, normalizer ----
        float n0 = 0.f, n1 = 0.f, n2 = 0.f, n3 = 0.f;
#pragma unroll
        for (int i = 0; i < 32; i += 4) {
            float d0 = fmaxf(z[i] - t, 0.f);
            float d1 = fmaxf(z[i + 1] - t, 0.f);
            float d2 = fmaxf(z[i + 2] - t, 0.f);
            float d3 = fmaxf(z[i + 3] - t, 0.f);
            d0 *= d0; d1 *= d1; d2 *= d2; d3 *= d3;
            n0 += d0; n1 += d1; n2 += d2; n3 += d3;
            z[i] = d0; z[i + 1] = d1; z[i + 2] = d2; z[i + 3] = d3;
        }
        float sn = (n0 + n1) + (n2 + n3);
        sn += __shfl_xor(sn, 1);
        sn += __shfl_xor(sn, 2);
        float inv = fastrcp(sn);

        // ---- scale by values, write out ----
        const float* vr = values + (size_t)(kh * O + orow) * F;
        float* op = out + (((size_t)b * K + kh) * O + orow) * (size_t)F;
#pragma unroll
        for (int j = 0; j < 8; ++j) {
            int fb = q * 4 + 16 * j;
            float4 vv = *(const float4*)(vr + fb);
            float4 ov;
            ov.x = z[4 * j + 0] * inv * vv.x;
            ov.y = z[4 * j + 1] * inv * vv.y;
            ov.z = z[4 * j + 2] * inv * vv.z;
            ov.w = z[4 * j + 3] * inv * vv.w;
            *(float4*)(op + fb) = ov;
        }
    }
}

extern "C" void kernel_launch(void* const* d_in, const int* in_sizes, int n_in,
                              void* d_out, int out_size, void* d_ws, size_t ws_size,
                              hipStream_t stream) {
    const float* x      = (const float*)d_in[0];   // [B, F, E]
    const float* Q      = (const float*)d_in[1];   // [K, O, E]
    const float* bil    = (const float*)d_in[2];   // [K, E, E]
    const float* values = (const float*)d_in[3];   // [K, O, F]
    float* out = (float*)d_out;                    // [B, K, O, F]

    unsigned short* Mhi = (unsigned short*)d_ws;           // [K][16][O][8] bf16 hi
    unsigned short* Mlo = Mhi + (size_t)K * O * E;         // same layout, lo

    precompute_M<<<(K * O * E) / 256, 256, 0, stream>>>(Q, bil, Mhi, Mlo);
    fused_entmax<<<BATCH, 256, 0, stream>>>(x, Mhi, Mlo, values, out);
}

// Round 8
// 258.786 us; speedup vs baseline: 1.5992x; 1.3489x over previous
//
#include <hip/hip_runtime.h>
#include <hip/hip_bf16.h>

#define E 128
#define F 128
#define O 64
#define K 8
#define BATCH 2048
#define NEWTON_IT 7

typedef __attribute__((ext_vector_type(8))) short bf8;     // 8 bf16 (4 VGPR)
typedef __attribute__((ext_vector_type(16))) float f16x;   // MFMA 32x32 accumulator

// ---------------------------------------------------------------------------
// Kernel A: M[k,o,x] = 0.5 * sum_y bil[k,x,y] * Q[k,o,y], stored as truncated
// bf16 hi/lo planes in FRAGMENT-MAJOR layout: [k][(s*2+h)][o][8] where
// x = s*16 + h*8 + e.  Kernel B's A-loads are then lane-coalesced.
// ---------------------------------------------------------------------------
__global__ __launch_bounds__(256) void precompute_M(const float* __restrict__ Q,
                                                    const float* __restrict__ bil,
                                                    unsigned short* __restrict__ Mhi,
                                                    unsigned short* __restrict__ Mlo) {
    int idx = blockIdx.x * 256 + threadIdx.x;   // ((kk*O + o)*E + x)
    int x  = idx & 127;
    int o  = (idx >> 7) & 63;
    int kk = idx >> 13;
    const float4* br = (const float4*)(bil + (size_t)(kk * E + x) * E);
    const float4* qr = (const float4*)(Q + (size_t)(kk * O + o) * E);
    float acc = 0.f;
#pragma unroll 8
    for (int y = 0; y < E / 4; ++y) {
        float4 bv = br[y], qv = qr[y];
        acc = fmaf(bv.x, qv.x, acc);
        acc = fmaf(bv.y, qv.y, acc);
        acc = fmaf(bv.z, qv.z, acc);
        acc = fmaf(bv.w, qv.w, acc);
    }
    float m = 0.5f * acc;
    unsigned um = __float_as_uint(m);
    float hi = __uint_as_float(um & 0xFFFF0000u);
    float lo = m - hi;
    int s = x >> 4, h = (x >> 3) & 1, e = x & 7;
    int nidx = kk * (O * E) + (((s * 2 + h) * 64 + o) << 3) + e;
    Mhi[nidx] = (unsigned short)(um >> 16);
    Mlo[nidx] = (unsigned short)(__float_as_uint(lo) >> 16);
}

// split a,b into truncated-bf16 hi words + lo words, packed pairwise
#define SPLIT_PK(a, b, hw, lw)                                              \
    {                                                                       \
        unsigned ua = __float_as_uint(a), ub = __float_as_uint(b);          \
        float la = (a) - __uint_as_float(ua & 0xFFFF0000u);                 \
        float lb = (b) - __uint_as_float(ub & 0xFFFF0000u);                 \
        hw = (ua >> 16) | (ub & 0xFFFF0000u);                               \
        lw = (__float_as_uint(la) >> 16) | (__float_as_uint(lb) & 0xFFFF0000u); \
    }

__device__ __forceinline__ float fastrcp(float x) {
    float r = __builtin_amdgcn_rcpf(x);
    return r * __builtin_fmaf(-x, r, 2.0f);   // 1 NR step -> ~f32-exact
}

// ---------------------------------------------------------------------------
// Kernel B: one block per b; x loaded+split ONCE into regs, then 8 heads:
// MFMA GEMM (3-product bf16 split) -> LDS transpose -> Newton entmax -> out.
// launch_bounds(256,3): VGPR cap 168 >> 76 used -> NO spill (the ,4 cap of
// round 7 forced 64 VGPR and +54MB scratch writes). LDS 33.8KB lets HW reach
// 4 blocks/CU on its own when registers allow.
// ---------------------------------------------------------------------------
__global__ __launch_bounds__(256, 3) void fused_entmax(
        const float* __restrict__ xg,
        const unsigned short* __restrict__ Mhi,
        const unsigned short* __restrict__ Mlo,
        const float* __restrict__ values,
        float* __restrict__ out) {
    __shared__ float lds[O * 132];           // 33792 B

    int b = blockIdx.x;
    const float* xb = xg + (size_t)b * (F * E);

    int tid  = threadIdx.x;
    int w    = tid >> 6, l = tid & 63;
    int lo31 = l & 31;
    int hl   = l >> 5;                       // K-half: x-chunk 0 or 8
    int fcol = w * 32 + lo31;

    // ---- B operand once per block: x[fcol][s*16+hl*8 .. +8), split hi/lo ----
    bf8 Bh[8], Bl[8];
#pragma unroll
    for (int s = 0; s < 8; ++s) {
        const float* p = xb + (size_t)fcol * E + s * 16 + hl * 8;
        float4 v0 = *(const float4*)p;
        float4 v1 = *(const float4*)(p + 4);
        union { bf8 v; unsigned u[4]; } H, L;
        SPLIT_PK(v0.x, v0.y, H.u[0], L.u[0]);
        SPLIT_PK(v0.z, v0.w, H.u[1], L.u[1]);
        SPLIT_PK(v1.x, v1.y, H.u[2], L.u[2]);
        SPLIT_PK(v1.z, v1.w, H.u[3], L.u[3]);
        Bh[s] = H.v;
        Bl[s] = L.v;
    }

    int orow = tid >> 2;
    int q    = tid & 3;

#pragma unroll 1
    for (int kh = 0; kh < K; ++kh) {
        const unsigned short* mh = Mhi + (size_t)kh * (O * E);
        const unsigned short* ml = Mlo + (size_t)kh * (O * E);

        // ---- MFMA K-loop: acc = Ah*Bh + Ah*Bl + Al*Bh (coalesced A-loads) ----
        f16x acc0{}, acc1{};
#pragma unroll
        for (int s = 0; s < 8; ++s) {
            int base = ((s * 2 + hl) * 64) << 3;
            bf8 a0h = *(const bf8*)(mh + base + (lo31 << 3));
            bf8 a0l = *(const bf8*)(ml + base + (lo31 << 3));
            bf8 a1h = *(const bf8*)(mh + base + ((lo31 + 32) << 3));
            bf8 a1l = *(const bf8*)(ml + base + ((lo31 + 32) << 3));
            acc0 = __builtin_amdgcn_mfma_f32_32x32x16_bf16(a0l, Bh[s], acc0, 0, 0, 0);
            acc0 = __builtin_amdgcn_mfma_f32_32x32x16_bf16(a0h, Bl[s], acc0, 0, 0, 0);
            acc0 = __builtin_amdgcn_mfma_f32_32x32x16_bf16(a0h, Bh[s], acc0, 0, 0, 0);
            acc1 = __builtin_amdgcn_mfma_f32_32x32x16_bf16(a1l, Bh[s], acc1, 0, 0, 0);
            acc1 = __builtin_amdgcn_mfma_f32_32x32x16_bf16(a1h, Bl[s], acc1, 0, 0, 0);
            acc1 = __builtin_amdgcn_mfma_f32_32x32x16_bf16(a1h, Bh[s], acc1, 0, 0, 0);
        }

        // ---- transpose C into lds[o][f] (stride 132) ----
        if (kh) __syncthreads();             // prev head's z-reads done
#pragma unroll
        for (int r = 0; r < 16; ++r) {
            int ol = (r & 3) + ((r >> 2) << 3) + (hl << 2);
            lds[ol * 132 + fcol]        = acc0[r];
            lds[(ol + 32) * 132 + fcol] = acc1[r];
        }
        __syncthreads();

        // ---- Newton entmax on row orow (128 elems across 4-lane quad) ----
        float z[32];
#pragma unroll
        for (int j = 0; j < 8; ++j) {
            float4 v = *(const float4*)&lds[orow * 132 + q * 4 + 16 * j];
            z[4 * j + 0] = v.x;
            z[4 * j + 1] = v.y;
            z[4 * j + 2] = v.z;
            z[4 * j + 3] = v.w;
        }

        float m0 = z[0], m1 = z[1], m2 = z[2], m3 = z[3];
#pragma unroll
        for (int i = 4; i < 32; i += 4) {
            m0 = fmaxf(m0, z[i]);
            m1 = fmaxf(m1, z[i + 1]);
            m2 = fmaxf(m2, z[i + 2]);
            m3 = fmaxf(m3, z[i + 3]);
        }
        float mx = fmaxf(fmaxf(m0, m1), fmaxf(m2, m3));
        mx = fmaxf(mx, __shfl_xor(mx, 1));
        mx = fmaxf(mx, __shfl_xor(mx, 2));

        float t = mx - 1.0f;
#pragma unroll
        for (int it = 0; it < NEWTON_IT; ++it) {
            float s0 = 0.f, s1 = 0.f, s2 = 0.f, s3 = 0.f;
            float a0 = 0.f, a1 = 0.f;
#pragma unroll
            for (int i = 0; i < 32; i += 4) {
                float d0 = fmaxf(z[i] - t, 0.f);
                float d1 = fmaxf(z[i + 1] - t, 0.f);
                float d2 = fmaxf(z[i + 2] - t, 0.f);
                float d3 = fmaxf(z[i + 3] - t, 0.f);
                s0 = __builtin_fmaf(d0, d0, s0);
                s1 = __builtin_fmaf(d1, d1, s1);
                s2 = __builtin_fmaf(d2, d2, s2);
                s3 = __builtin_fmaf(d3, d3, s3);
                a0 += d0 + d1;
                a1 += d2 + d3;
            }
            float fs = (s0 + s1) + (s2 + s3);
            float sl = a0 + a1;
            fs += __shfl_xor(fs, 1);
            fs += __shfl_xor(fs, 2);
            sl += __shfl_xor(sl, 1);
            sl += __shfl_xor(sl, 2);
            t += (fs - 1.0f) * 0.5f * fastrcp(sl);   // convex, from below
        }

        // ---- final eval: d^2 in place, normalizer ----
        float n0 = 0.f, n1 = 0.f, n2 = 0.f, n3 = 0.f;
#pragma unroll
        for (int i = 0; i < 32; i += 4) {
            float d0 = fmaxf(z[i] - t, 0.f);
            float d1 = fmaxf(z[i + 1] - t, 0.f);
            float d2 = fmaxf(z[i + 2] - t, 0.f);
            float d3 = fmaxf(z[i + 3] - t, 0.f);
            d0 *= d0; d1 *= d1; d2 *= d2; d3 *= d3;
            n0 += d0; n1 += d1; n2 += d2; n3 += d3;
            z[i] = d0; z[i + 1] = d1; z[i + 2] = d2; z[i + 3] = d3;
        }
        float sn = (n0 + n1) + (n2 + n3);
        sn += __shfl_xor(sn, 1);
        sn += __shfl_xor(sn, 2);
        float inv = fastrcp(sn);

        // ---- scale by values, write out ----
        const float* vr = values + (size_t)(kh * O + orow) * F;
        float* op = out + (((size_t)b * K + kh) * O + orow) * (size_t)F;
#pragma unroll
        for (int j = 0; j < 8; ++j) {
            int fb = q * 4 + 16 * j;
            float4 vv = *(const float4*)(vr + fb);
            float4 ov;
            ov.x = z[4 * j + 0] * inv * vv.x;
            ov.y = z[4 * j + 1] * inv * vv.y;
            ov.z = z[4 * j + 2] * inv * vv.z;
            ov.w = z[4 * j + 3] * inv * vv.w;
            *(float4*)(op + fb) = ov;
        }
    }
}

extern "C" void kernel_launch(void* const* d_in, const int* in_sizes, int n_in,
                              void* d_out, int out_size, void* d_ws, size_t ws_size,
                              hipStream_t stream) {
    const float* x      = (const float*)d_in[0];   // [B, F, E]
    const float* Q      = (const float*)d_in[1];   // [K, O, E]
    const float* bil    = (const float*)d_in[2];   // [K, E, E]
    const float* values = (const float*)d_in[3];   // [K, O, F]
    float* out = (float*)d_out;                    // [B, K, O, F]

    unsigned short* Mhi = (unsigned short*)d_ws;           // [K][16][O][8] bf16 hi
    unsigned short* Mlo = Mhi + (size_t)K * O * E;         // same layout, lo

    precompute_M<<<(K * O * E) / 256, 256, 0, stream>>>(Q, bil, Mhi, Mlo);
    fused_entmax<<<BATCH, 256, 0, stream>>>(x, Mhi, Mlo, values, out);
}

// Round 9
// 251.754 us; speedup vs baseline: 1.6439x; 1.0279x over previous
//
#include <hip/hip_runtime.h>
#include <hip/hip_bf16.h>

#define E 128
#define F 128
#define O 64
#define K 8
#define BATCH 2048
#define NEWTON_IT 6

typedef __attribute__((ext_vector_type(8))) short bf8;     // 8 bf16 (4 VGPR)
typedef __attribute__((ext_vector_type(16))) float f16x;   // MFMA 32x32 accumulator

// ---------------------------------------------------------------------------
// Kernel A: M[k,o,x] = 0.5 * sum_y bil[k,x,y] * Q[k,o,y], stored as truncated
// bf16 hi/lo planes in FRAGMENT-MAJOR layout: [k][(s*2+h)][o][8] where
// x = s*16 + h*8 + e.  Kernel B's A-loads are then lane-coalesced.
// ---------------------------------------------------------------------------
__global__ __launch_bounds__(256) void precompute_M(const float* __restrict__ Q,
                                                    const float* __restrict__ bil,
                                                    unsigned short* __restrict__ Mhi,
                                                    unsigned short* __restrict__ Mlo) {
    int idx = blockIdx.x * 256 + threadIdx.x;   // ((kk*O + o)*E + x)
    int x  = idx & 127;
    int o  = (idx >> 7) & 63;
    int kk = idx >> 13;
    const float4* br = (const float4*)(bil + (size_t)(kk * E + x) * E);
    const float4* qr = (const float4*)(Q + (size_t)(kk * O + o) * E);
    float acc = 0.f;
#pragma unroll 8
    for (int y = 0; y < E / 4; ++y) {
        float4 bv = br[y], qv = qr[y];
        acc = fmaf(bv.x, qv.x, acc);
        acc = fmaf(bv.y, qv.y, acc);
        acc = fmaf(bv.z, qv.z, acc);
        acc = fmaf(bv.w, qv.w, acc);
    }
    float m = 0.5f * acc;
    unsigned um = __float_as_uint(m);
    float hi = __uint_as_float(um & 0xFFFF0000u);
    float lo = m - hi;
    int s = x >> 4, h = (x >> 3) & 1, e = x & 7;
    int nidx = kk * (O * E) + (((s * 2 + h) * 64 + o) << 3) + e;
    Mhi[nidx] = (unsigned short)(um >> 16);
    Mlo[nidx] = (unsigned short)(__float_as_uint(lo) >> 16);
}

// split a,b into truncated-bf16 hi words + lo words, packed pairwise
#define SPLIT_PK(a, b, hw, lw)                                              \
    {                                                                       \
        unsigned ua = __float_as_uint(a), ub = __float_as_uint(b);          \
        float la = (a) - __uint_as_float(ua & 0xFFFF0000u);                 \
        float lb = (b) - __uint_as_float(ub & 0xFFFF0000u);                 \
        hw = (ua >> 16) | (ub & 0xFFFF0000u);                               \
        lw = (__float_as_uint(la) >> 16) | (__float_as_uint(lb) & 0xFFFF0000u); \
    }

__device__ __forceinline__ float fastrcp(float x) {
    float r = __builtin_amdgcn_rcpf(x);
    return r * __builtin_fmaf(-x, r, 2.0f);   // 1 NR step -> ~f32-exact
}

// ---------------------------------------------------------------------------
// Kernel B: one block per b; x loaded+split ONCE into regs, then 8 heads:
// MFMA GEMM (3-product bf16 split) -> LDS transpose -> Newton entmax -> out.
// LDS tile is [64][128] floats with XOR bank-swizzle f ^ ((row&7)<<2):
// exactly 32768 B -> 5 blocks/CU (stride-132 pad gave only 4). Writes and
// reads are both 2-way-per-bank (free). launch_bounds(256,3) keeps the
// allocator at cap 168 (round 7 proved a tighter cap forces spills).
// ---------------------------------------------------------------------------
__global__ __launch_bounds__(256, 3) void fused_entmax(
        const float* __restrict__ xg,
        const unsigned short* __restrict__ Mhi,
        const unsigned short* __restrict__ Mlo,
        const float* __restrict__ values,
        float* __restrict__ out) {
    __shared__ float lds[O * 128];           // 32768 B exactly

    int b = blockIdx.x;
    const float* xb = xg + (size_t)b * (F * E);

    int tid  = threadIdx.x;
    int w    = tid >> 6, l = tid & 63;
    int lo31 = l & 31;
    int hl   = l >> 5;                       // K-half: x-chunk 0 or 8
    int fcol = w * 32 + lo31;

    // ---- B operand once per block: x[fcol][s*16+hl*8 .. +8), split hi/lo ----
    bf8 Bh[8], Bl[8];
#pragma unroll
    for (int s = 0; s < 8; ++s) {
        const float* p = xb + (size_t)fcol * E + s * 16 + hl * 8;
        float4 v0 = *(const float4*)p;
        float4 v1 = *(const float4*)(p + 4);
        union { bf8 v; unsigned u[4]; } H, L;
        SPLIT_PK(v0.x, v0.y, H.u[0], L.u[0]);
        SPLIT_PK(v0.z, v0.w, H.u[1], L.u[1]);
        SPLIT_PK(v1.x, v1.y, H.u[2], L.u[2]);
        SPLIT_PK(v1.z, v1.w, H.u[3], L.u[3]);
        Bh[s] = H.v;
        Bl[s] = L.v;
    }

    int orow = tid >> 2;
    int q    = tid & 3;
    int rsw  = (orow & 7) << 2;              // read-side bank swizzle

#pragma unroll 1
    for (int kh = 0; kh < K; ++kh) {
        const unsigned short* mh = Mhi + (size_t)kh * (O * E);
        const unsigned short* ml = Mlo + (size_t)kh * (O * E);

        // ---- MFMA K-loop: acc = Ah*Bh + Ah*Bl + Al*Bh (coalesced A-loads) ----
        f16x acc0{}, acc1{};
#pragma unroll
        for (int s = 0; s < 8; ++s) {
            int base = ((s * 2 + hl) * 64) << 3;
            bf8 a0h = *(const bf8*)(mh + base + (lo31 << 3));
            bf8 a0l = *(const bf8*)(ml + base + (lo31 << 3));
            bf8 a1h = *(const bf8*)(mh + base + ((lo31 + 32) << 3));
            bf8 a1l = *(const bf8*)(ml + base + ((lo31 + 32) << 3));
            acc0 = __builtin_amdgcn_mfma_f32_32x32x16_bf16(a0l, Bh[s], acc0, 0, 0, 0);
            acc0 = __builtin_amdgcn_mfma_f32_32x32x16_bf16(a0h, Bl[s], acc0, 0, 0, 0);
            acc0 = __builtin_amdgcn_mfma_f32_32x32x16_bf16(a0h, Bh[s], acc0, 0, 0, 0);
            acc1 = __builtin_amdgcn_mfma_f32_32x32x16_bf16(a1l, Bh[s], acc1, 0, 0, 0);
            acc1 = __builtin_amdgcn_mfma_f32_32x32x16_bf16(a1h, Bl[s], acc1, 0, 0, 0);
            acc1 = __builtin_amdgcn_mfma_f32_32x32x16_bf16(a1h, Bh[s], acc1, 0, 0, 0);
        }

        // ---- transpose C into lds[o][f ^ ((o&7)<<2)] ----
        if (kh) __syncthreads();             // prev head's z-reads done
#pragma unroll
        for (int r = 0; r < 16; ++r) {
            int ol = (r & 3) + ((r >> 2) << 3) + (hl << 2);
            int fs = fcol ^ ((ol & 7) << 2);
            lds[ol * 128 + fs]        = acc0[r];
            lds[(ol + 32) * 128 + fs] = acc1[r];
        }
        __syncthreads();

        // ---- Newton entmax on row orow (128 elems across 4-lane quad) ----
        float z[32];
#pragma unroll
        for (int j = 0; j < 8; ++j) {
            float4 v = *(const float4*)&lds[orow * 128 + ((q * 4 + 16 * j) ^ rsw)];
            z[4 * j + 0] = v.x;
            z[4 * j + 1] = v.y;
            z[4 * j + 2] = v.z;
            z[4 * j + 3] = v.w;
        }

        float m0 = z[0], m1 = z[1], m2 = z[2], m3 = z[3];
#pragma unroll
        for (int i = 4; i < 32; i += 4) {
            m0 = fmaxf(m0, z[i]);
            m1 = fmaxf(m1, z[i + 1]);
            m2 = fmaxf(m2, z[i + 2]);
            m3 = fmaxf(m3, z[i + 3]);
        }
        float mx = fmaxf(fmaxf(m0, m1), fmaxf(m2, m3));
        mx = fmaxf(mx, __shfl_xor(mx, 1));
        mx = fmaxf(mx, __shfl_xor(mx, 2));

        float t = mx - 1.0f;
#pragma unroll
        for (int it = 0; it < NEWTON_IT; ++it) {
            float s0 = 0.f, s1 = 0.f, s2 = 0.f, s3 = 0.f;
            float a0 = 0.f, a1 = 0.f;
#pragma unroll
            for (int i = 0; i < 32; i += 4) {
                float d0 = fmaxf(z[i] - t, 0.f);
                float d1 = fmaxf(z[i + 1] - t, 0.f);
                float d2 = fmaxf(z[i + 2] - t, 0.f);
                float d3 = fmaxf(z[i + 3] - t, 0.f);
                s0 = __builtin_fmaf(d0, d0, s0);
                s1 = __builtin_fmaf(d1, d1, s1);
                s2 = __builtin_fmaf(d2, d2, s2);
                s3 = __builtin_fmaf(d3, d3, s3);
                a0 += d0 + d1;
                a1 += d2 + d3;
            }
            float fs = (s0 + s1) + (s2 + s3);
            float sl = a0 + a1;
            fs += __shfl_xor(fs, 1);
            fs += __shfl_xor(fs, 2);
            sl += __shfl_xor(sl, 1);
            sl += __shfl_xor(sl, 2);
            t += (fs - 1.0f) * 0.5f * fastrcp(sl);   // convex, from below
        }

        // ---- final eval: d^2 in place, normalizer ----
        float n0 = 0.f, n1 = 0.f, n2 = 0.f, n3 = 0.f;
#pragma unroll
        for (int i = 0; i < 32; i += 4) {
            float d0 = fmaxf(z[i] - t, 0.f);
            float d1 = fmaxf(z[i + 1] - t, 0.f);
            float d2 = fmaxf(z[i + 2] - t, 0.f);
            float d3 = fmaxf(z[i + 3] - t, 0.f);
            d0 *= d0; d1 *= d1; d2 *= d2; d3 *= d3;
            n0 += d0; n1 += d1; n2 += d2; n3 += d3;
            z[i] = d0; z[i + 1] = d1; z[i + 2] = d2; z[i + 3] = d3;
        }
        float sn = (n0 + n1) + (n2 + n3);
        sn += __shfl_xor(sn, 1);
        sn += __shfl_xor(sn, 2);
        float inv = fastrcp(sn);

        // ---- scale by values, write out ----
        const float* vr = values + (size_t)(kh * O + orow) * F;
        float* op = out + (((size_t)b * K + kh) * O + orow) * (size_t)F;
#pragma unroll
        for (int j = 0; j < 8; ++j) {
            int fb = q * 4 + 16 * j;
            float4 vv = *(const float4*)(vr + fb);
            float4 ov;
            ov.x = z[4 * j + 0] * inv * vv.x;
            ov.y = z[4 * j + 1] * inv * vv.y;
            ov.z = z[4 * j + 2] * inv * vv.z;
            ov.w = z[4 * j + 3] * inv * vv.w;
            *(float4*)(op + fb) = ov;
        }
    }
}

extern "C" void kernel_launch(void* const* d_in, const int* in_sizes, int n_in,
                              void* d_out, int out_size, void* d_ws, size_t ws_size,
                              hipStream_t stream) {
    const float* x      = (const float*)d_in[0];   // [B, F, E]
    const float* Q      = (const float*)d_in[1];   // [K, O, E]
    const float* bil    = (const float*)d_in[2];   // [K, E, E]
    const float* values = (const float*)d_in[3];   // [K, O, F]
    float* out = (float*)d_out;                    // [B, K, O, F]

    unsigned short* Mhi = (unsigned short*)d_ws;           // [K][16][O][8] bf16 hi
    unsigned short* Mlo = Mhi + (size_t)K * O * E;         // same layout, lo

    precompute_M<<<(K * O * E) / 256, 256, 0, stream>>>(Q, bil, Mhi, Mlo);
    fused_entmax<<<BATCH, 256, 0, stream>>>(x, Mhi, Mlo, values, out);
}

// Round 10
// 242.251 us; speedup vs baseline: 1.7084x; 1.0392x over previous
//
#include <hip/hip_runtime.h>
#include <hip/hip_bf16.h>

#define E 128
#define F 128
#define O 64
#define K 8
#define BATCH 2048
#define NEWTON_IT 6

typedef __attribute__((ext_vector_type(8))) short bf8;     // 8 bf16 (4 VGPR)
typedef __attribute__((ext_vector_type(16))) float f16x;   // MFMA 32x32 accumulator

// ---------------------------------------------------------------------------
// Kernel A: M[k,o,x] = 0.5 * sum_y bil[k,x,y] * Q[k,o,y], truncated-bf16
// hi/lo split, packed per head as ONE contiguous 32 KB chunk:
//   head k: [hi: [16][64][8] shorts][lo: same]   (fragment-major, x=s*16+h*8+e)
// so kernel B can stage a whole head with a single linear float4 copy.
// ---------------------------------------------------------------------------
__global__ __launch_bounds__(256) void precompute_M(const float* __restrict__ Q,
                                                    const float* __restrict__ bil,
                                                    unsigned short* __restrict__ Mws) {
    int idx = blockIdx.x * 256 + threadIdx.x;   // ((kk*O + o)*E + x)
    int x  = idx & 127;
    int o  = (idx >> 7) & 63;
    int kk = idx >> 13;
    const float4* br = (const float4*)(bil + (size_t)(kk * E + x) * E);
    const float4* qr = (const float4*)(Q + (size_t)(kk * O + o) * E);
    float acc = 0.f;
#pragma unroll 8
    for (int y = 0; y < E / 4; ++y) {
        float4 bv = br[y], qv = qr[y];
        acc = fmaf(bv.x, qv.x, acc);
        acc = fmaf(bv.y, qv.y, acc);
        acc = fmaf(bv.z, qv.z, acc);
        acc = fmaf(bv.w, qv.w, acc);
    }
    float m = 0.5f * acc;
    unsigned um = __float_as_uint(m);
    float hi = __uint_as_float(um & 0xFFFF0000u);
    float lo = m - hi;
    int s = x >> 4, h = (x >> 3) & 1, e = x & 7;
    int local = (((s * 2 + h) * 64 + o) << 3) + e;      // 0..8191
    unsigned short* hp = Mws + (size_t)kk * 16384;      // head base (shorts)
    unsigned short hw = (unsigned short)(um >> 16);
    unsigned short lw = (unsigned short)(__float_as_uint(lo) >> 16);
    hp[local]        = hw;
    hp[8192 + local] = lw;
}

// split a,b into truncated-bf16 hi words + lo words, packed pairwise
#define SPLIT_PK(a, b, hw, lw)                                              \
    {                                                                       \
        unsigned ua = __float_as_uint(a), ub = __float_as_uint(b);          \
        float la = (a) - __uint_as_float(ua & 0xFFFF0000u);                 \
        float lb = (b) - __uint_as_float(ub & 0xFFFF0000u);                 \
        hw = (ua >> 16) | (ub & 0xFFFF0000u);                               \
        lw = (__float_as_uint(la) >> 16) | (__float_as_uint(lb) & 0xFFFF0000u); \
    }

__device__ __forceinline__ float fastrcp(float x) {
    float r = __builtin_amdgcn_rcpf(x);
    return r * __builtin_fmaf(-x, r, 2.0f);   // 1 NR step -> ~f32-exact
}

// ---------------------------------------------------------------------------
// Kernel B: one block per b; x loaded+split once. Per head: stage M (32 KB)
// into LDS once per BLOCK (kills the 4x-per-wave L2 redundancy: 2 GB -> 512
// MB), MFMA with ds_read A-fragments, transpose C into the SAME buffer (M is
// dead), Newton entmax, write out. LDS stays 32 KB -> 5 blocks/CU.
// ---------------------------------------------------------------------------
__global__ __launch_bounds__(256, 3) void fused_entmax(
        const float* __restrict__ xg,
        const unsigned short* __restrict__ Mws,
        const float* __restrict__ values,
        float* __restrict__ out) {
    __shared__ float4 buf[2048];             // 32768 B: M-stage / z-tile (time-shared)
    float* lds = (float*)buf;
    unsigned short* ldsM = (unsigned short*)buf;

    int b = blockIdx.x;
    const float* xb = xg + (size_t)b * (F * E);

    int tid  = threadIdx.x;
    int w    = tid >> 6, l = tid & 63;
    int lo31 = l & 31;
    int hl   = l >> 5;                       // K-half: x-chunk 0 or 8
    int fcol = w * 32 + lo31;

    // ---- B operand once per block: x[fcol][s*16+hl*8 .. +8), split hi/lo ----
    bf8 Bh[8], Bl[8];
#pragma unroll
    for (int s = 0; s < 8; ++s) {
        const float* p = xb + (size_t)fcol * E + s * 16 + hl * 8;
        float4 v0 = *(const float4*)p;
        float4 v1 = *(const float4*)(p + 4);
        union { bf8 v; unsigned u[4]; } H, L;
        SPLIT_PK(v0.x, v0.y, H.u[0], L.u[0]);
        SPLIT_PK(v0.z, v0.w, H.u[1], L.u[1]);
        SPLIT_PK(v1.x, v1.y, H.u[2], L.u[2]);
        SPLIT_PK(v1.z, v1.w, H.u[3], L.u[3]);
        Bh[s] = H.v;
        Bl[s] = L.v;
    }

    int orow = tid >> 2;
    int q    = tid & 3;
    int rsw  = (orow & 7) << 2;              // read-side bank swizzle

#pragma unroll 1
    for (int kh = 0; kh < K; ++kh) {
        // ---- stage head's M (32 KB) into LDS: linear coalesced copy ----
        if (kh) __syncthreads();             // prev head's z-loads done
        {
            const float4* src = (const float4*)(Mws + (size_t)kh * 16384);
#pragma unroll
            for (int i = 0; i < 8; ++i)
                buf[i * 256 + tid] = src[i * 256 + tid];
        }
        __syncthreads();

        // ---- MFMA K-loop: A-fragments from LDS (conflict-free b128) ----
        f16x acc0{}, acc1{};
#pragma unroll
        for (int s = 0; s < 8; ++s) {
            int base = ((s * 2 + hl) * 64) << 3;
            bf8 a0h = *(const bf8*)(ldsM + base + (lo31 << 3));
            bf8 a0l = *(const bf8*)(ldsM + 8192 + base + (lo31 << 3));
            bf8 a1h = *(const bf8*)(ldsM + base + ((lo31 + 32) << 3));
            bf8 a1l = *(const bf8*)(ldsM + 8192 + base + ((lo31 + 32) << 3));
            acc0 = __builtin_amdgcn_mfma_f32_32x32x16_bf16(a0l, Bh[s], acc0, 0, 0, 0);
            acc0 = __builtin_amdgcn_mfma_f32_32x32x16_bf16(a0h, Bl[s], acc0, 0, 0, 0);
            acc0 = __builtin_amdgcn_mfma_f32_32x32x16_bf16(a0h, Bh[s], acc0, 0, 0, 0);
            acc1 = __builtin_amdgcn_mfma_f32_32x32x16_bf16(a1l, Bh[s], acc1, 0, 0, 0);
            acc1 = __builtin_amdgcn_mfma_f32_32x32x16_bf16(a1h, Bl[s], acc1, 0, 0, 0);
            acc1 = __builtin_amdgcn_mfma_f32_32x32x16_bf16(a1h, Bh[s], acc1, 0, 0, 0);
        }
        __syncthreads();                     // all A-reads done; M now dead

        // ---- transpose C into lds[o][f ^ ((o&7)<<2)] (overwrites M) ----
#pragma unroll
        for (int r = 0; r < 16; ++r) {
            int ol = (r & 3) + ((r >> 2) << 3) + (hl << 2);
            int fs = fcol ^ ((ol & 7) << 2);
            lds[ol * 128 + fs]        = acc0[r];
            lds[(ol + 32) * 128 + fs] = acc1[r];
        }
        __syncthreads();

        // ---- Newton entmax on row orow (128 elems across 4-lane quad) ----
        float z[32];
#pragma unroll
        for (int j = 0; j < 8; ++j) {
            float4 v = *(const float4*)&lds[orow * 128 + ((q * 4 + 16 * j) ^ rsw)];
            z[4 * j + 0] = v.x;
            z[4 * j + 1] = v.y;
            z[4 * j + 2] = v.z;
            z[4 * j + 3] = v.w;
        }

        float m0 = z[0], m1 = z[1], m2 = z[2], m3 = z[3];
#pragma unroll
        for (int i = 4; i < 32; i += 4) {
            m0 = fmaxf(m0, z[i]);
            m1 = fmaxf(m1, z[i + 1]);
            m2 = fmaxf(m2, z[i + 2]);
            m3 = fmaxf(m3, z[i + 3]);
        }
        float mx = fmaxf(fmaxf(m0, m1), fmaxf(m2, m3));
        mx = fmaxf(mx, __shfl_xor(mx, 1));
        mx = fmaxf(mx, __shfl_xor(mx, 2));

        float t = mx - 1.0f;
#pragma unroll
        for (int it = 0; it < NEWTON_IT; ++it) {
            float s0 = 0.f, s1 = 0.f, s2 = 0.f, s3 = 0.f;
            float a0 = 0.f, a1 = 0.f;
#pragma unroll
            for (int i = 0; i < 32; i += 4) {
                float d0 = fmaxf(z[i] - t, 0.f);
                float d1 = fmaxf(z[i + 1] - t, 0.f);
                float d2 = fmaxf(z[i + 2] - t, 0.f);
                float d3 = fmaxf(z[i + 3] - t, 0.f);
                s0 = __builtin_fmaf(d0, d0, s0);
                s1 = __builtin_fmaf(d1, d1, s1);
                s2 = __builtin_fmaf(d2, d2, s2);
                s3 = __builtin_fmaf(d3, d3, s3);
                a0 += d0 + d1;
                a1 += d2 + d3;
            }
            float fs = (s0 + s1) + (s2 + s3);
            float sl = a0 + a1;
            fs += __shfl_xor(fs, 1);
            fs += __shfl_xor(fs, 2);
            sl += __shfl_xor(sl, 1);
            sl += __shfl_xor(sl, 2);
            t += (fs - 1.0f) * 0.5f * fastrcp(sl);   // convex, from below
        }

        // ---- final eval: d^2 in place, normalizer ----
        float n0 = 0.f, n1 = 0.f, n2 = 0.f, n3 = 0.f;
#pragma unroll
        for (int i = 0; i < 32; i += 4) {
            float d0 = fmaxf(z[i] - t, 0.f);
            float d1 = fmaxf(z[i + 1] - t, 0.f);
            float d2 = fmaxf(z[i + 2] - t, 0.f);
            float d3 = fmaxf(z[i + 3] - t, 0.f);
            d0 *= d0; d1 *= d1; d2 *= d2; d3 *= d3;
            n0 += d0; n1 += d1; n2 += d2; n3 += d3;
            z[i] = d0; z[i + 1] = d1; z[i + 2] = d2; z[i + 3] = d3;
        }
        float sn = (n0 + n1) + (n2 + n3);
        sn += __shfl_xor(sn, 1);
        sn += __shfl_xor(sn, 2);
        float inv = fastrcp(sn);

        // ---- scale by values, write out ----
        const float* vr = values + (size_t)(kh * O + orow) * F;
        float* op = out + (((size_t)b * K + kh) * O + orow) * (size_t)F;
#pragma unroll
        for (int j = 0; j < 8; ++j) {
            int fb = q * 4 + 16 * j;
            float4 vv = *(const float4*)(vr + fb);
            float4 ov;
            ov.x = z[4 * j + 0] * inv * vv.x;
            ov.y = z[4 * j + 1] * inv * vv.y;
            ov.z = z[4 * j + 2] * inv * vv.z;
            ov.w = z[4 * j + 3] * inv * vv.w;
            *(float4*)(op + fb) = ov;
        }
    }
}

extern "C" void kernel_launch(void* const* d_in, const int* in_sizes, int n_in,
                              void* d_out, int out_size, void* d_ws, size_t ws_size,
                              hipStream_t stream) {
    const float* x      = (const float*)d_in[0];   // [B, F, E]
    const float* Q      = (const float*)d_in[1];   // [K, O, E]
    const float* bil    = (const float*)d_in[2];   // [K, E, E]
    const float* values = (const float*)d_in[3];   // [K, O, F]
    float* out = (float*)d_out;                    // [B, K, O, F]

    unsigned short* Mws = (unsigned short*)d_ws;   // K heads x 32 KB (hi|lo)

    precompute_M<<<(K * O * E) / 256, 256, 0, stream>>>(Q, bil, Mws);
    fused_entmax<<<BATCH, 256, 0, stream>>>(x, Mws, values, out);
}

// Round 11
// 238.686 us; speedup vs baseline: 1.7339x; 1.0149x over previous
//
#include <hip/hip_runtime.h>
#include <hip/hip_bf16.h>

#define E 128
#define F 128
#define O 64
#define K 8
#define BATCH 2048
#define NEWTON_IT 6

typedef __attribute__((ext_vector_type(8))) short bf8;     // 8 bf16 (4 VGPR)
typedef __attribute__((ext_vector_type(16))) float f16x;   // MFMA 32x32 accumulator
typedef __attribute__((ext_vector_type(2))) float f2;      // packed f32 (VOP3P)

// ---------------------------------------------------------------------------
// Kernel A: M[k,o,x] = 0.5 * sum_y bil[k,x,y] * Q[k,o,y], truncated-bf16
// hi/lo split, packed per head as ONE contiguous 32 KB chunk:
//   head k: [hi: [16][64][8] shorts][lo: same]   (fragment-major, x=s*16+h*8+e)
// so kernel B can stage a whole head with a single linear float4 copy.
// ---------------------------------------------------------------------------
__global__ __launch_bounds__(256) void precompute_M(const float* __restrict__ Q,
                                                    const float* __restrict__ bil,
                                                    unsigned short* __restrict__ Mws) {
    int idx = blockIdx.x * 256 + threadIdx.x;   // ((kk*O + o)*E + x)
    int x  = idx & 127;
    int o  = (idx >> 7) & 63;
    int kk = idx >> 13;
    const float4* br = (const float4*)(bil + (size_t)(kk * E + x) * E);
    const float4* qr = (const float4*)(Q + (size_t)(kk * O + o) * E);
    float acc = 0.f;
#pragma unroll 8
    for (int y = 0; y < E / 4; ++y) {
        float4 bv = br[y], qv = qr[y];
        acc = fmaf(bv.x, qv.x, acc);
        acc = fmaf(bv.y, qv.y, acc);
        acc = fmaf(bv.z, qv.z, acc);
        acc = fmaf(bv.w, qv.w, acc);
    }
    float m = 0.5f * acc;
    unsigned um = __float_as_uint(m);
    float hi = __uint_as_float(um & 0xFFFF0000u);
    float lo = m - hi;
    int s = x >> 4, h = (x >> 3) & 1, e = x & 7;
    int local = (((s * 2 + h) * 64 + o) << 3) + e;      // 0..8191
    unsigned short* hp = Mws + (size_t)kk * 16384;      // head base (shorts)
    hp[local]        = (unsigned short)(um >> 16);
    hp[8192 + local] = (unsigned short)(__float_as_uint(lo) >> 16);
}

// split a,b into truncated-bf16 hi words + lo words, packed pairwise
#define SPLIT_PK(a, b, hw, lw)                                              \
    {                                                                       \
        unsigned ua = __float_as_uint(a), ub = __float_as_uint(b);          \
        float la = (a) - __uint_as_float(ua & 0xFFFF0000u);                 \
        float lb = (b) - __uint_as_float(ub & 0xFFFF0000u);                 \
        hw = (ua >> 16) | (ub & 0xFFFF0000u);                               \
        lw = (__float_as_uint(la) >> 16) | (__float_as_uint(lb) & 0xFFFF0000u); \
    }

__device__ __forceinline__ float fastrcp(float x) {
    float r = __builtin_amdgcn_rcpf(x);
    return r * __builtin_fmaf(-x, r, 2.0f);   // 1 NR step -> ~f32-exact
}

// ---------------------------------------------------------------------------
// Kernel B: one block per b; x loaded+split once. Per head: stage M (32 KB)
// into LDS once per block, MFMA with ds_read A-fragments, transpose C into
// the same buffer (M dead), Newton entmax in PACKED f32 (v_pk_fma/add/mul),
// write out. LDS 32 KB -> 5 blocks/CU; launch_bounds(256,3) -> no spill.
// ---------------------------------------------------------------------------
__global__ __launch_bounds__(256, 3) void fused_entmax(
        const float* __restrict__ xg,
        const unsigned short* __restrict__ Mws,
        const float* __restrict__ values,
        float* __restrict__ out) {
    __shared__ float4 buf[2048];             // 32768 B: M-stage / z-tile (time-shared)
    float* lds = (float*)buf;
    unsigned short* ldsM = (unsigned short*)buf;

    int b = blockIdx.x;
    const float* xb = xg + (size_t)b * (F * E);

    int tid  = threadIdx.x;
    int w    = tid >> 6, l = tid & 63;
    int lo31 = l & 31;
    int hl   = l >> 5;                       // K-half: x-chunk 0 or 8
    int fcol = w * 32 + lo31;

    // ---- B operand once per block: x[fcol][s*16+hl*8 .. +8), split hi/lo ----
    bf8 Bh[8], Bl[8];
#pragma unroll
    for (int s = 0; s < 8; ++s) {
        const float* p = xb + (size_t)fcol * E + s * 16 + hl * 8;
        float4 v0 = *(const float4*)p;
        float4 v1 = *(const float4*)(p + 4);
        union { bf8 v; unsigned u[4]; } H, L;
        SPLIT_PK(v0.x, v0.y, H.u[0], L.u[0]);
        SPLIT_PK(v0.z, v0.w, H.u[1], L.u[1]);
        SPLIT_PK(v1.x, v1.y, H.u[2], L.u[2]);
        SPLIT_PK(v1.z, v1.w, H.u[3], L.u[3]);
        Bh[s] = H.v;
        Bl[s] = L.v;
    }

    int orow = tid >> 2;
    int q    = tid & 3;
    int rsw  = (orow & 7) << 2;              // read-side bank swizzle
    const f2 zero2 = {0.f, 0.f};

#pragma unroll 1
    for (int kh = 0; kh < K; ++kh) {
        // ---- stage head's M (32 KB) into LDS: linear coalesced copy ----
        if (kh) __syncthreads();             // prev head's z-loads done
        {
            const float4* src = (const float4*)(Mws + (size_t)kh * 16384);
#pragma unroll
            for (int i = 0; i < 8; ++i)
                buf[i * 256 + tid] = src[i * 256 + tid];
        }
        __syncthreads();

        // ---- MFMA K-loop: A-fragments from LDS (conflict-free b128) ----
        f16x acc0{}, acc1{};
#pragma unroll
        for (int s = 0; s < 8; ++s) {
            int base = ((s * 2 + hl) * 64) << 3;
            bf8 a0h = *(const bf8*)(ldsM + base + (lo31 << 3));
            bf8 a0l = *(const bf8*)(ldsM + 8192 + base + (lo31 << 3));
            bf8 a1h = *(const bf8*)(ldsM + base + ((lo31 + 32) << 3));
            bf8 a1l = *(const bf8*)(ldsM + 8192 + base + ((lo31 + 32) << 3));
            acc0 = __builtin_amdgcn_mfma_f32_32x32x16_bf16(a0l, Bh[s], acc0, 0, 0, 0);
            acc0 = __builtin_amdgcn_mfma_f32_32x32x16_bf16(a0h, Bl[s], acc0, 0, 0, 0);
            acc0 = __builtin_amdgcn_mfma_f32_32x32x16_bf16(a0h, Bh[s], acc0, 0, 0, 0);
            acc1 = __builtin_amdgcn_mfma_f32_32x32x16_bf16(a1l, Bh[s], acc1, 0, 0, 0);
            acc1 = __builtin_amdgcn_mfma_f32_32x32x16_bf16(a1h, Bl[s], acc1, 0, 0, 0);
            acc1 = __builtin_amdgcn_mfma_f32_32x32x16_bf16(a1h, Bh[s], acc1, 0, 0, 0);
        }
        __syncthreads();                     // all A-reads done; M now dead

        // ---- transpose C into lds[o][f ^ ((o&7)<<2)] (overwrites M) ----
#pragma unroll
        for (int r = 0; r < 16; ++r) {
            int ol = (r & 3) + ((r >> 2) << 3) + (hl << 2);
            int fs = fcol ^ ((ol & 7) << 2);
            lds[ol * 128 + fs]        = acc0[r];
            lds[(ol + 32) * 128 + fs] = acc1[r];
        }
        __syncthreads();

        // ---- load row orow as packed f2 (128 elems across 4-lane quad) ----
        f2 z2[16];
#pragma unroll
        for (int j = 0; j < 8; ++j) {
            float4 v = *(const float4*)&lds[orow * 128 + ((q * 4 + 16 * j) ^ rsw)];
            z2[2 * j]     = f2{v.x, v.y};
            z2[2 * j + 1] = f2{v.z, v.w};
        }

        // ---- row max ----
        f2 mm0 = z2[0], mm1 = z2[1], mm2 = z2[2], mm3 = z2[3];
#pragma unroll
        for (int i = 4; i < 16; i += 4) {
            mm0 = __builtin_elementwise_max(mm0, z2[i]);
            mm1 = __builtin_elementwise_max(mm1, z2[i + 1]);
            mm2 = __builtin_elementwise_max(mm2, z2[i + 2]);
            mm3 = __builtin_elementwise_max(mm3, z2[i + 3]);
        }
        mm0 = __builtin_elementwise_max(__builtin_elementwise_max(mm0, mm1),
                                        __builtin_elementwise_max(mm2, mm3));
        float mx = fmaxf(mm0.x, mm0.y);
        mx = fmaxf(mx, __shfl_xor(mx, 1));
        mx = fmaxf(mx, __shfl_xor(mx, 2));

        // ---- Newton on f(t)=sum relu(z-t)^2-1 from t0=mx-1 (packed eval) ----
        float t = mx - 1.0f;
#pragma unroll
        for (int it = 0; it < NEWTON_IT; ++it) {
            f2 tt = {t, t};
            f2 sA = zero2, sB = zero2, lA = zero2, lB = zero2;
#pragma unroll
            for (int i = 0; i < 16; i += 2) {
                f2 d0 = __builtin_elementwise_max(z2[i] - tt, zero2);
                f2 d1 = __builtin_elementwise_max(z2[i + 1] - tt, zero2);
                sA = d0 * d0 + sA;           // v_pk_fma_f32
                sB = d1 * d1 + sB;
                lA += d0;                    // v_pk_add_f32
                lB += d1;
            }
            f2 sv = sA + sB;
            f2 lv = lA + lB;
            float fs = sv.x + sv.y;
            float sl = lv.x + lv.y;
            fs += __shfl_xor(fs, 1);
            fs += __shfl_xor(fs, 2);
            sl += __shfl_xor(sl, 1);
            sl += __shfl_xor(sl, 2);
            t += (fs - 1.0f) * 0.5f * fastrcp(sl);   // convex, from below
        }

        // ---- final eval: d^2 in place (packed), normalizer ----
        {
            f2 tt = {t, t};
            f2 nA = zero2, nB = zero2;
#pragma unroll
            for (int i = 0; i < 16; i += 2) {
                f2 d0 = __builtin_elementwise_max(z2[i] - tt, zero2);
                f2 d1 = __builtin_elementwise_max(z2[i + 1] - tt, zero2);
                d0 *= d0;                    // v_pk_mul_f32
                d1 *= d1;
                nA += d0;
                nB += d1;
                z2[i] = d0;
                z2[i + 1] = d1;
            }
            f2 nv = nA + nB;
            float sn = nv.x + nv.y;
            sn += __shfl_xor(sn, 1);
            sn += __shfl_xor(sn, 2);
            float inv = fastrcp(sn);

            // ---- scale by values, write out (packed muls) ----
            f2 iv = {inv, inv};
            const float* vr = values + (size_t)(kh * O + orow) * F;
            float* op = out + (((size_t)b * K + kh) * O + orow) * (size_t)F;
#pragma unroll
            for (int j = 0; j < 8; ++j) {
                int fb = q * 4 + 16 * j;
                float4 vv = *(const float4*)(vr + fb);
                f2 a = z2[2 * j] * iv;
                f2 c = z2[2 * j + 1] * iv;
                a *= f2{vv.x, vv.y};
                c *= f2{vv.z, vv.w};
                float4 ov = {a.x, a.y, c.x, c.y};
                *(float4*)(op + fb) = ov;
            }
        }
    }
}

extern "C" void kernel_launch(void* const* d_in, const int* in_sizes, int n_in,
                              void* d_out, int out_size, void* d_ws, size_t ws_size,
                              hipStream_t stream) {
    const float* x      = (const float*)d_in[0];   // [B, F, E]
    const float* Q      = (const float*)d_in[1];   // [K, O, E]
    const float* bil    = (const float*)d_in[2];   // [K, E, E]
    const float* values = (const float*)d_in[3];   // [K, O, F]
    float* out = (float*)d_out;                    // [B, K, O, F]

    unsigned short* Mws = (unsigned short*)d_ws;   // K heads x 32 KB (hi|lo)

    precompute_M<<<(K * O * E) / 256, 256, 0, stream>>>(Q, bil, Mws);
    fused_entmax<<<BATCH, 256, 0, stream>>>(x, Mws, values, out);
}